// Round 3
// baseline (39659.134 us; speedup 1.0000x reference)
//
#include <hip/hip_runtime.h>
#include <math.h>

// ---------------------------------------------------------------------------
// VRNN on MI355X.  Round 3: batch-partitioned, sync-free scan.
// Key fact: the recurrence is elementwise in the batch dim (no cross-row
// mixing). 16 blocks x 16 rows each run all 200 steps privately:
//   * h + all intermediates live in LDS (~77 KB/block), weights via normal
//     caches (L2/LLC hot), NO grid barriers, NO coherence traffic.
//   * Block = 1024 threads (16 waves, 4/SIMD) for latency hiding.
//   * GRU = 3 fused K-passes (pz@ih_pz + px@ih_px + h@hh) into registers.
// Batched pre/post passes unchanged in structure; gemm tile 64x128.
// ---------------------------------------------------------------------------

#define TT 200
#define BB 256
#define HD 512
#define TB (TT*BB)   // 51200

typedef unsigned short u16;
typedef __attribute__((ext_vector_type(8))) short bf16x8;
typedef __attribute__((ext_vector_type(4))) float f32x4;

// output layout (fp32, concatenated flat): z, logits, em, es, pm, ps, kld
constexpr size_t OFF_Z      = 0;
constexpr size_t OFF_LOGITS = 3276800;
constexpr size_t OFF_EM     = 16384000;
constexpr size_t OFF_ES     = 19660800;
constexpr size_t OFF_PM     = 22937600;
constexpr size_t OFF_PS     = 26214400;
constexpr size_t OFF_KLD    = 29491200;

__device__ __forceinline__ u16 f2bf(float f) {
  union { float f; unsigned u; } v; v.f = f;
  return (u16)((v.u + 0x7fffu + ((v.u >> 16) & 1u)) >> 16);  // RNE
}
__device__ __forceinline__ float bf2f(u16 b) {
  union { unsigned u; float f; } v; v.u = ((unsigned)b) << 16; return v.f;
}
__device__ __forceinline__ float sp_(float x) { return (x > 15.f) ? x : log1pf(expf(x)); }
__device__ __forceinline__ float sigm_(float x) { return 1.f / (1.f + expf(-x)); }

#define MFMA(a,b,c) __builtin_amdgcn_mfma_f32_16x16x32_bf16((a),(b),(c),0,0,0)

// ---------------------------------------------------------------------------
// weight cast+transpose: dst[c*R + r] = bf16(src[r*C + c])   (dst is [C][R])
// ---------------------------------------------------------------------------
#define NSEG 18
struct CastSeg { const float* src; u16* dst; int R; int C; };
struct CastArgs { CastSeg seg[NSEG]; };

__global__ __launch_bounds__(256) void cast_all(CastArgs a) {
  int idx = blockIdx.x * 256 + threadIdx.x;
  #pragma unroll 1
  for (int s = 0; s < NSEG; s++) {
    const int R = a.seg[s].R, C = a.seg[s].C;
    const int sz = R * C;
    if (idx < sz) {
      const int r = idx / C, c = idx - r * C;
      a.seg[s].dst[(size_t)c * R + r] = f2bf(a.seg[s].src[idx]);
      return;
    }
    idx -= sz;
  }
}

// zero H[0] (prior head at t=0 reads h=0)
__global__ __launch_bounds__(256) void init_k(u16* H0) {
  const int i = blockIdx.x * 256 + threadIdx.x;
  if (i < BB * HD) H0[i] = 0;
}

// ---------------------------------------------------------------------------
// batched GEMM:  out = act( A1@Bt1^T [+ A2@Bt2^T] + bias )
// A1: [TB][K1] (bf16, or fp32 if a1f32), Bt: [N][K] bf16 (pre-transposed).
// Tile: 64 rows x 128 cols per block; wave v -> rows m0+16v; 8 col-tiles.
// ---------------------------------------------------------------------------
struct GB {
  const void* A1; int lda1, K1, a1f32;
  const u16* Bt1;
  const u16* A2; int lda2, K2;
  const u16* Bt2;
  const float* bias;
  u16* outB; float* outF; int ldc;
  int tilesN; int act;   // act: 0 none, 1 relu
};

__device__ __forceinline__ bf16x8 load_a8(const void* A, int f32, size_t row, int lda, int k) {
  if (!f32) return *(const bf16x8*)((const u16*)A + row * (size_t)lda + k);
  const float* p = (const float*)A + row * (size_t)lda + k;
  f32x4 x0 = *(const f32x4*)p;
  f32x4 x1 = *(const f32x4*)(p + 4);
  bf16x8 r;
  r[0]=(short)f2bf(x0[0]); r[1]=(short)f2bf(x0[1]); r[2]=(short)f2bf(x0[2]); r[3]=(short)f2bf(x0[3]);
  r[4]=(short)f2bf(x1[0]); r[5]=(short)f2bf(x1[1]); r[6]=(short)f2bf(x1[2]); r[7]=(short)f2bf(x1[3]);
  return r;
}

__global__ __launch_bounds__(256) void gemm_bt(GB g) {
  const int tn = blockIdx.x % g.tilesN, tm = blockIdx.x / g.tilesN;
  const int m0 = tm * 64, n0 = tn * 128;
  const int v = threadIdx.x >> 6, l = threadIdx.x & 63, lm = l & 15, q = l >> 4;
  const size_t rowA = m0 + v * 16 + lm;
  f32x4 acc[8] = {};
  for (int k0 = 0; k0 < g.K1; k0 += 32) {
    bf16x8 a = load_a8(g.A1, g.a1f32, rowA, g.lda1, k0 + q * 8);
    #pragma unroll
    for (int c = 0; c < 8; c++) {
      bf16x8 b = *(const bf16x8*)(g.Bt1 + (size_t)(n0 + c * 16 + lm) * g.K1 + k0 + q * 8);
      acc[c] = MFMA(a, b, acc[c]);
    }
  }
  if (g.A2) {
    for (int k0 = 0; k0 < g.K2; k0 += 32) {
      bf16x8 a = *(const bf16x8*)(g.A2 + rowA * (size_t)g.lda2 + k0 + q * 8);
      #pragma unroll
      for (int c = 0; c < 8; c++) {
        bf16x8 b = *(const bf16x8*)(g.Bt2 + (size_t)(n0 + c * 16 + lm) * g.K2 + k0 + q * 8);
        acc[c] = MFMA(a, b, acc[c]);
      }
    }
  }
  #pragma unroll
  for (int c = 0; c < 8; c++) {
    const int col = n0 + c * 16 + lm;
    const float bs = g.bias ? g.bias[col] : 0.f;
    #pragma unroll
    for (int r = 0; r < 4; r++) {
      const size_t row = (size_t)m0 + v * 16 + q * 4 + r;
      float x = acc[c][r] + bs;
      if (g.act == 1) x = fmaxf(x, 0.f);
      if (g.outB) g.outB[row * g.ldc + col] = f2bf(x);
      if (g.outF) g.outF[row * g.ldc + col] = x;
    }
  }
}

// ---------------------------------------------------------------------------
// prior mean/std heads + kld, fused.  PR:[TB][512] bf16, pms_t:[128][512]
// ---------------------------------------------------------------------------
__global__ __launch_bounds__(256) void pms_kld(const u16* PR, const u16* pms_t,
                                               const float* pmb, const float* psb,
                                               float* out) {
  const int m0 = blockIdx.x * 64;
  const int v = threadIdx.x >> 6, l = threadIdx.x & 63, lm = l & 15, q = l >> 4;
  const size_t rowA = m0 + v * 16 + lm;
  f32x4 acc[8] = {};
  for (int k0 = 0; k0 < 512; k0 += 32) {
    bf16x8 a = *(const bf16x8*)(PR + rowA * 512 + k0 + q * 8);
    #pragma unroll
    for (int c = 0; c < 8; c++) {
      bf16x8 b = *(const bf16x8*)(pms_t + (size_t)(c * 16 + lm) * 512 + k0 + q * 8);
      acc[c] = MFMA(a, b, acc[c]);
    }
  }
  #pragma unroll
  for (int c = 0; c < 4; c++) {
    const int colz = c * 16 + lm;
    #pragma unroll
    for (int r = 0; r < 4; r++) {
      const size_t row = (size_t)m0 + v * 16 + q * 4 + r;
      const float pm = acc[c][r] + pmb[colz];
      const float ps = sp_(acc[c + 4][r] + psb[colz]);
      const size_t oi = row * 64 + colz;
      const float em = out[OFF_EM + oi], es = out[OFF_ES + oi];
      const float d = em - pm;
      const float kld = 0.5f * (2.f * logf(ps) - 2.f * logf(es)
                                + (es * es + d * d) / (ps * ps) - 1.f);
      out[OFF_PM + oi] = pm;
      out[OFF_PS + oi] = ps;
      out[OFF_KLD + oi] = kld;
    }
  }
}

// ---------------------------------------------------------------------------
// scan: 16 blocks x 1024 threads; block owns rows [16*blockIdx, +16).
// ---------------------------------------------------------------------------
struct SC {
  const u16 *pre_enc, *px;
  u16 *H, *PZ;
  const u16 *enc_w1_h_t, *enc_w2_t, *ems_t, *phi_z_t, *gru_hh_t, *gru_ih_pz_t, *gru_ih_px_t;
  const float *enc_b2, *enc_mean_b, *enc_std_b, *phi_z_b, *gru_b_ih, *gru_b_hh;
  const float *eps;
  float *out;
};

#define PITCH 520   // 16-row LDS tiles, +8 elem pad (row stride 1040 B, 16B-aligned)

__global__ __launch_bounds__(1024) void scan_k(SC s) {
  const int w = threadIdx.x >> 6, l = threadIdx.x & 63, lm = l & 15, q = l >> 4;
  const int r0 = blockIdx.x * 16;
  __shared__ u16 h_bf[16 * PITCH];
  __shared__ u16 A_l [16 * PITCH];
  __shared__ u16 E_l [16 * PITCH];
  __shared__ u16 pz_l[16 * PITCH];
  __shared__ float ems_l[16 * 128];
  __shared__ u16 z_l[16 * 72];

  for (int i = threadIdx.x; i < 16 * PITCH; i += 1024) h_bf[i] = 0;
  float hreg[2][4] = {{0.f,0.f,0.f,0.f},{0.f,0.f,0.f,0.f}};

  // per-wave column assignments & constant biases (persist across t)
  const int jc0 = 32 * w + lm, jc1 = 32 * w + 16 + lm;
  const float b2c0 = s.enc_b2[jc0],  b2c1 = s.enc_b2[jc1];
  const float pzb0 = s.phi_z_b[jc0], pzb1 = s.phi_z_b[jc1];
  const float brg0 = s.gru_b_ih[jc0] + s.gru_b_hh[jc0];
  const float brg1 = s.gru_b_ih[jc1] + s.gru_b_hh[jc1];
  const float bug0 = s.gru_b_ih[512 + jc0] + s.gru_b_hh[512 + jc0];
  const float bug1 = s.gru_b_ih[512 + jc1] + s.gru_b_hh[512 + jc1];
  const float bxn0 = s.gru_b_ih[1024 + jc0], bxn1 = s.gru_b_ih[1024 + jc1];
  const float bhn0 = s.gru_b_hh[1024 + jc0], bhn1 = s.gru_b_hh[1024 + jc1];
  const int zrow = threadIdx.x >> 6, zcc = threadIdx.x & 63;
  const float emb = s.enc_mean_b[zcc], esb = s.enc_std_b[zcc];
  __syncthreads();

  for (int t = 0; t < TT; t++) {
    const size_t tb = (size_t)t * BB + r0;   // global row base for this step

    // ---- A = relu(pre_enc[t] + h @ enc_w1_h) ----------------------------
    {
      u16 pre0[4], pre1[4];
      #pragma unroll
      for (int r = 0; r < 4; r++) {
        pre0[r] = s.pre_enc[(tb + q * 4 + r) * 512 + jc0];
        pre1[r] = s.pre_enc[(tb + q * 4 + r) * 512 + jc1];
      }
      f32x4 a0 = {}, a1 = {};
      for (int k0 = 0; k0 < 512; k0 += 32) {
        bf16x8 a  = *(const bf16x8*)(h_bf + lm * PITCH + k0 + q * 8);
        bf16x8 b0 = *(const bf16x8*)(s.enc_w1_h_t + (size_t)jc0 * 512 + k0 + q * 8);
        bf16x8 b1 = *(const bf16x8*)(s.enc_w1_h_t + (size_t)jc1 * 512 + k0 + q * 8);
        a0 = MFMA(a, b0, a0); a1 = MFMA(a, b1, a1);
      }
      #pragma unroll
      for (int r = 0; r < 4; r++) {
        A_l[(q * 4 + r) * PITCH + jc0] = f2bf(fmaxf(a0[r] + bf2f(pre0[r]), 0.f));
        A_l[(q * 4 + r) * PITCH + jc1] = f2bf(fmaxf(a1[r] + bf2f(pre1[r]), 0.f));
      }
    }
    __syncthreads();

    // ---- E = relu(A @ enc_w2 + b2) --------------------------------------
    {
      f32x4 a0 = {}, a1 = {};
      for (int k0 = 0; k0 < 512; k0 += 32) {
        bf16x8 a  = *(const bf16x8*)(A_l + lm * PITCH + k0 + q * 8);
        bf16x8 b0 = *(const bf16x8*)(s.enc_w2_t + (size_t)jc0 * 512 + k0 + q * 8);
        bf16x8 b1 = *(const bf16x8*)(s.enc_w2_t + (size_t)jc1 * 512 + k0 + q * 8);
        a0 = MFMA(a, b0, a0); a1 = MFMA(a, b1, a1);
      }
      #pragma unroll
      for (int r = 0; r < 4; r++) {
        E_l[(q * 4 + r) * PITCH + jc0] = f2bf(fmaxf(a0[r] + b2c0, 0.f));
        E_l[(q * 4 + r) * PITCH + jc1] = f2bf(fmaxf(a1[r] + b2c1, 0.f));
      }
    }
    __syncthreads();

    // ---- ems = E @ ems_t  (waves 0..7; 128 cols; bias added in z phase) --
    if (w < 8) {
      f32x4 a0 = {};
      for (int k0 = 0; k0 < 512; k0 += 32) {
        bf16x8 a = *(const bf16x8*)(E_l + lm * PITCH + k0 + q * 8);
        bf16x8 b = *(const bf16x8*)(s.ems_t + (size_t)(16 * w + lm) * 512 + k0 + q * 8);
        a0 = MFMA(a, b, a0);
      }
      #pragma unroll
      for (int r = 0; r < 4; r++) ems_l[(q * 4 + r) * 128 + 16 * w + lm] = a0[r];
    }
    __syncthreads();

    // ---- z = eps*softplus(es)+em ; write z/em/es to out ------------------
    {
      const float em = ems_l[zrow * 128 + zcc] + emb;
      const float es = sp_(ems_l[zrow * 128 + 64 + zcc] + esb);
      const size_t oi = (tb + zrow) * 64 + zcc;
      const float z = s.eps[oi] * es + em;
      s.out[OFF_Z + oi] = z;
      s.out[OFF_EM + oi] = em;
      s.out[OFF_ES + oi] = es;
      z_l[zrow * 72 + zcc] = f2bf(z);
    }
    __syncthreads();

    // ---- pz = relu(z @ phi_z + b); keep in LDS + store for post-pass -----
    {
      f32x4 p0 = {}, p1 = {};
      #pragma unroll
      for (int k0 = 0; k0 < 64; k0 += 32) {
        bf16x8 a  = *(const bf16x8*)(z_l + lm * 72 + k0 + q * 8);
        bf16x8 b0 = *(const bf16x8*)(s.phi_z_t + (size_t)jc0 * 64 + k0 + q * 8);
        bf16x8 b1 = *(const bf16x8*)(s.phi_z_t + (size_t)jc1 * 64 + k0 + q * 8);
        p0 = MFMA(a, b0, p0); p1 = MFMA(a, b1, p1);
      }
      #pragma unroll
      for (int r = 0; r < 4; r++) {
        const u16 v0 = f2bf(fmaxf(p0[r] + pzb0, 0.f));
        const u16 v1 = f2bf(fmaxf(p1[r] + pzb1, 0.f));
        pz_l[(q * 4 + r) * PITCH + jc0] = v0;
        pz_l[(q * 4 + r) * PITCH + jc1] = v1;
        s.PZ[(tb + q * 4 + r) * 512 + jc0] = v0;
        s.PZ[(tb + q * 4 + r) * 512 + jc1] = v1;
      }
    }
    __syncthreads();

    // ---- GRU: acc = pz@ih_pz + px@ih_px (x-parts) ; h@hh (r,u merged; hn sep)
    {
      f32x4 ar0 = {}, ar1 = {}, au0 = {}, au1 = {}, axn0 = {}, axn1 = {}, ahn0 = {}, ahn1 = {};
      for (int k0 = 0; k0 < 512; k0 += 32) {
        bf16x8 a = *(const bf16x8*)(pz_l + lm * PITCH + k0 + q * 8);
        const u16* B = s.gru_ih_pz_t;
        ar0  = MFMA(a, *(const bf16x8*)(B + (size_t)jc0 * 512 + k0 + q * 8), ar0);
        ar1  = MFMA(a, *(const bf16x8*)(B + (size_t)jc1 * 512 + k0 + q * 8), ar1);
        au0  = MFMA(a, *(const bf16x8*)(B + (size_t)(512 + jc0) * 512 + k0 + q * 8), au0);
        au1  = MFMA(a, *(const bf16x8*)(B + (size_t)(512 + jc1) * 512 + k0 + q * 8), au1);
        axn0 = MFMA(a, *(const bf16x8*)(B + (size_t)(1024 + jc0) * 512 + k0 + q * 8), axn0);
        axn1 = MFMA(a, *(const bf16x8*)(B + (size_t)(1024 + jc1) * 512 + k0 + q * 8), axn1);
      }
      for (int k0 = 0; k0 < 512; k0 += 32) {
        bf16x8 a = *(const bf16x8*)(s.px + (tb + lm) * 512 + k0 + q * 8);
        const u16* B = s.gru_ih_px_t;
        ar0  = MFMA(a, *(const bf16x8*)(B + (size_t)jc0 * 512 + k0 + q * 8), ar0);
        ar1  = MFMA(a, *(const bf16x8*)(B + (size_t)jc1 * 512 + k0 + q * 8), ar1);
        au0  = MFMA(a, *(const bf16x8*)(B + (size_t)(512 + jc0) * 512 + k0 + q * 8), au0);
        au1  = MFMA(a, *(const bf16x8*)(B + (size_t)(512 + jc1) * 512 + k0 + q * 8), au1);
        axn0 = MFMA(a, *(const bf16x8*)(B + (size_t)(1024 + jc0) * 512 + k0 + q * 8), axn0);
        axn1 = MFMA(a, *(const bf16x8*)(B + (size_t)(1024 + jc1) * 512 + k0 + q * 8), axn1);
      }
      for (int k0 = 0; k0 < 512; k0 += 32) {
        bf16x8 a = *(const bf16x8*)(h_bf + lm * PITCH + k0 + q * 8);
        const u16* B = s.gru_hh_t;
        ar0  = MFMA(a, *(const bf16x8*)(B + (size_t)jc0 * 512 + k0 + q * 8), ar0);
        ar1  = MFMA(a, *(const bf16x8*)(B + (size_t)jc1 * 512 + k0 + q * 8), ar1);
        au0  = MFMA(a, *(const bf16x8*)(B + (size_t)(512 + jc0) * 512 + k0 + q * 8), au0);
        au1  = MFMA(a, *(const bf16x8*)(B + (size_t)(512 + jc1) * 512 + k0 + q * 8), au1);
        ahn0 = MFMA(a, *(const bf16x8*)(B + (size_t)(1024 + jc0) * 512 + k0 + q * 8), ahn0);
        ahn1 = MFMA(a, *(const bf16x8*)(B + (size_t)(1024 + jc1) * 512 + k0 + q * 8), ahn1);
      }
      __syncthreads();   // all reads of h_bf/pz_l done before h_bf overwrite
      #pragma unroll
      for (int r = 0; r < 4; r++) {
        const int row = q * 4 + r;
        {
          const float rg = sigm_(ar0[r] + brg0);
          const float uu = sigm_(au0[r] + bug0);
          const float nn = tanhf(axn0[r] + bxn0 + rg * (ahn0[r] + bhn0));
          const float hn_ = (1.f - uu) * nn + uu * hreg[0][r];
          hreg[0][r] = hn_;
          const u16 hb = f2bf(hn_);
          h_bf[row * PITCH + jc0] = hb;
          if (t < TT - 1)
            s.H[(size_t)(t + 1) * (BB * HD) + (size_t)(r0 + row) * 512 + jc0] = hb;
        }
        {
          const float rg = sigm_(ar1[r] + brg1);
          const float uu = sigm_(au1[r] + bug1);
          const float nn = tanhf(axn1[r] + bxn1 + rg * (ahn1[r] + bhn1));
          const float hn_ = (1.f - uu) * nn + uu * hreg[1][r];
          hreg[1][r] = hn_;
          const u16 hb = f2bf(hn_);
          h_bf[row * PITCH + jc1] = hb;
          if (t < TT - 1)
            s.H[(size_t)(t + 1) * (BB * HD) + (size_t)(r0 + row) * 512 + jc1] = hb;
        }
      }
    }
    __syncthreads();
  }
}

// ---------------------------------------------------------------------------
extern "C" void kernel_launch(void* const* d_in, const int* in_sizes, int n_in,
                              void* d_out, int out_size, void* d_ws, size_t ws_size,
                              hipStream_t stream) {
  (void)in_sizes; (void)n_in; (void)out_size; (void)ws_size;
  char* ws = (char*)d_ws;
  float* out = (float*)d_out;
  auto in = [&](int i) { return (const float*)d_in[i]; };

  size_t o = 0;
  auto take = [&](size_t bytes) { size_t r = o; o += (bytes + 255) & ~(size_t)255; return r; };
  const size_t oPhiXW1  = take(512 * 128 * 2);
  const size_t oPhiXW2  = take(512 * 512 * 2);
  const size_t oEncW1px = take(512 * 512 * 2);
  const size_t oEncW1h  = take(512 * 512 * 2);
  const size_t oEncW2   = take(512 * 512 * 2);
  const size_t oEms     = take(128 * 512 * 2);
  const size_t oPhiZ    = take(512 * 64 * 2);
  const size_t oPriorW  = take(512 * 512 * 2);
  const size_t oPriorMs = take(128 * 512 * 2);
  const size_t oDecW1pz = take(512 * 512 * 2);
  const size_t oDecW1h  = take(512 * 512 * 2);
  const size_t oDecW2   = take(512 * 512 * 2);
  const size_t oDecLog  = take(256 * 512 * 2);
  const size_t oGruIhPx = take((size_t)1536 * 512 * 2);
  const size_t oGruIhPz = take((size_t)1536 * 512 * 2);
  const size_t oGruHh   = take((size_t)1536 * 512 * 2);
  const size_t oBuf0    = take((size_t)TB * 512 * 2);
  const size_t oBuf1    = take((size_t)TB * 512 * 2);
  const size_t oH       = take((size_t)TB * 512 * 2);
  const size_t oPZ      = take((size_t)TB * 512 * 2);

  auto W = [&](size_t off) { return (u16*)(ws + off); };
  u16* BUF0 = W(oBuf0);
  u16* BUF1 = W(oBuf1);
  u16* Hbuf = W(oH);
  u16* PZbuf = W(oPZ);

  // --- weight cast+transpose (one kernel, 18 segments) ---
  CastArgs ca;
  int si = 0;
  auto seg = [&](const float* src, u16* dst, int R, int C) { ca.seg[si++] = {src, dst, R, C}; };
  seg(in(2), W(oPhiXW1), 128, 512);
  seg(in(4), W(oPhiXW2), 512, 512);
  seg(in(8), W(oEncW1px), 512, 512);
  seg(in(8) + 512 * 512, W(oEncW1h), 512, 512);
  seg(in(10), W(oEncW2), 512, 512);
  seg(in(12), W(oEms), 512, 64);
  seg(in(14), W(oEms) + 64 * 512, 512, 64);
  seg(in(6), W(oPhiZ), 64, 512);
  seg(in(16), W(oPriorW), 512, 512);
  seg(in(18), W(oPriorMs), 512, 64);
  seg(in(20), W(oPriorMs) + 64 * 512, 512, 64);
  seg(in(22), W(oDecW1pz), 512, 512);
  seg(in(22) + 512 * 512, W(oDecW1h), 512, 512);
  seg(in(24), W(oDecW2), 512, 512);
  seg(in(26), W(oDecLog), 512, 256);
  seg(in(28), W(oGruIhPx), 512, 1536);
  seg(in(28) + 512 * 1536, W(oGruIhPz), 512, 1536);
  seg(in(30), W(oGruHh), 512, 1536);
  hipLaunchKernelGGL(cast_all, dim3(18816), dim3(256), 0, stream, ca);
  hipLaunchKernelGGL(init_k, dim3(512), dim3(256), 0, stream, Hbuf);

  auto gemm = [&](const void* A1, int lda1, int K1, int a1f32, const u16* Bt1,
                  const u16* A2, int lda2, int K2, const u16* Bt2,
                  const float* bias, u16* outB, float* outF, int ldc, int N, int act) {
    GB g;
    g.A1 = A1; g.lda1 = lda1; g.K1 = K1; g.a1f32 = a1f32; g.Bt1 = Bt1;
    g.A2 = A2; g.lda2 = lda2; g.K2 = K2; g.Bt2 = Bt2;
    g.bias = bias; g.outB = outB; g.outF = outF; g.ldc = ldc;
    g.tilesN = N / 128; g.act = act;
    hipLaunchKernelGGL(gemm_bt, dim3((TB / 64) * (N / 128)), dim3(256), 0, stream, g);
  };

  // --- pre-pass ---
  // PX1 = relu(x @ phi_x_w1 + b1)          -> BUF0
  gemm(in(0), 128, 128, 1, W(oPhiXW1), nullptr, 0, 0, nullptr, in(3), BUF0, nullptr, 512, 512, 1);
  // PX  = relu(PX1 @ phi_x_w2 + b2)        -> BUF1
  gemm(BUF0, 512, 512, 0, W(oPhiXW2), nullptr, 0, 0, nullptr, in(5), BUF1, nullptr, 512, 512, 1);
  // PRE_ENC = PX @ enc_w1[:512] + enc_b1   -> BUF0
  gemm(BUF1, 512, 512, 0, W(oEncW1px), nullptr, 0, 0, nullptr, in(9), BUF0, nullptr, 512, 512, 0);

  // --- sequential scan (16 independent blocks, no grid sync) ---
  SC sc;
  sc.pre_enc = BUF0; sc.px = BUF1;
  sc.H = Hbuf; sc.PZ = PZbuf;
  sc.enc_w1_h_t = W(oEncW1h); sc.enc_w2_t = W(oEncW2); sc.ems_t = W(oEms);
  sc.phi_z_t = W(oPhiZ); sc.gru_hh_t = W(oGruHh);
  sc.gru_ih_pz_t = W(oGruIhPz); sc.gru_ih_px_t = W(oGruIhPx);
  sc.enc_b2 = in(11); sc.enc_mean_b = in(13); sc.enc_std_b = in(15);
  sc.phi_z_b = in(7); sc.gru_b_ih = in(29); sc.gru_b_hh = in(31);
  sc.eps = in(1); sc.out = out;
  hipLaunchKernelGGL(scan_k, dim3(16), dim3(1024), 0, stream, sc);

  // --- post-pass (batched over all T) ---
  // PR = relu(Hprev @ prior_w + b)         -> BUF0 (pre_enc dead after scan)
  gemm(Hbuf, 512, 512, 0, W(oPriorW), nullptr, 0, 0, nullptr, in(17), BUF0, nullptr, 512, 512, 1);
  // pm/ps/kld                              -> d_out
  hipLaunchKernelGGL(pms_kld, dim3(TB / 64), dim3(256), 0, stream,
                     BUF0, W(oPriorMs), in(19), in(21), out);
  // DH1 = relu(PZ@dec_w1[:512] + Hprev@dec_w1[512:] + b1) -> BUF1 (px dead)
  gemm(PZbuf, 512, 512, 0, W(oDecW1pz), Hbuf, 512, 512, W(oDecW1h), in(23), BUF1, nullptr, 512, 512, 1);
  // D = relu(DH1 @ dec_w2 + b2)            -> BUF0
  gemm(BUF1, 512, 512, 0, W(oDecW2), nullptr, 0, 0, nullptr, in(25), BUF0, nullptr, 512, 512, 1);
  // logits = D @ dec_logits + b            -> d_out fp32
  gemm(BUF0, 512, 512, 0, W(oDecLog), nullptr, 0, 0, nullptr, in(27), nullptr, out + OFF_LOGITS, 256, 256, 0);
}